// Round 8
// baseline (1650.934 us; speedup 1.0000x reference)
//
#include <hip/hip_runtime.h>

// 2-layer stacked LSTM: B=256, T=2048, H=64, layer2 hidden=1.
// One block per batch element (256 blocks), 320 threads (5 waves).
//
// Consolidated model from rounds 1-7:
//  (1) DS pipe is per-op (~6-12 cyc each), so per-lane h delivery from LDS
//      (64 b128 reads/CU/step in r1-r4) is a ~770 cyc/step floor.
//  (2) The allocator honors register demand only when <=64 VGPRs (r5: 48,
//      r7: 44); above that it squeezes to 64 and re-fetches weights per
//      step (r1-r4, r6). Attributes never lifted the budget.
//  (3) Each LDS write->barrier->read round trip on the recurrence is ~240
//      cyc; allow exactly ONE per step.
// This design: every wave redundantly computes the full c1/h1 update
// (lane l = unit l) from one small gate exchange, so h1 is replicated in
// registers of all waves and never transits LDS. Layer-1 dot = 64 x
// (v_readlane + v_fmac) per wave (uniform lane index, VALU pipe, no serial
// chain). Weights: 32 in arch VGPRs + 32 in AGPRs via explicit
// v_accvgpr_write/read asm (AGPRs are a separate budget on gfx950 and an
// asm def cannot be rematerialized) -> arch demand ~52 < 64.
//
// Waves 0-3: gate w for all 64 units (lane l = column l of gate w).
// Wave 4: layer 2, 2-stage pipeline (stage A: butterfly dot for t-1;
//   stage B: recurrent c2/h2 update for t-2); also does the redundant
//   c1/h1 update like everyone else. Outputs staged in out_lds.
// ONE __syncthreads per step.
constexpr int kT = 2048;
constexpr int kB = 256;
constexpr int kH = 64;
constexpr int kThreads = 320;

__device__ __forceinline__ float fast_sig(float x) {
    return __builtin_amdgcn_rcpf(1.0f + __expf(-x));
}
__device__ __forceinline__ float fast_tanh(float x) {
    float t = __expf(2.0f * x);
    return 1.0f - 2.0f * __builtin_amdgcn_rcpf(t + 1.0f);
}
__device__ __forceinline__ float rlane(float v, int k) {
    // broadcast lane k of v through an SGPR (VALU pipe, uniform index)
    return __int_as_float(__builtin_amdgcn_readlane(__float_as_int(v), k));
}

__global__ __launch_bounds__(kThreads) void lstm2_kernel(
    const float* __restrict__ x, const float* __restrict__ W1,
    const float* __restrict__ b1, const float* __restrict__ W2,
    const float* __restrict__ b2, float* __restrict__ out)
{
    __shared__ float x_lds[kT];          // input row
    __shared__ float out_lds[kT];        // staged outputs
    __shared__ float a_lds[2][4 * kH];   // double-buffered activated gates

    const int tid = threadIdx.x;
    const int b = blockIdx.x;
    const float* xg = x + (size_t)b * kT;
    float* outg = out + (size_t)b * kT;

    for (int i = tid; i < kT; i += kThreads) x_lds[i] = xg[i];

    const int w = tid >> 6;   // wave 0..4
    const int l = tid & 63;   // lane = unit (and column-within-gate)

    // ---- layer-1 weights: rows 1..32 in VGPRs, rows 33..64 in AGPRs ----
    float wqv[32];
    float wqa[32];            // each element pinned to an AGPR by asm def
    #pragma unroll
    for (int k = 0; k < 32; ++k) wqv[k] = 0.0f;
    float w0 = 0.f, b1g = 0.f;
    float c1 = 0.f, h_new = 0.f;   // replicated in every wave, lane = unit

    // ---- layer-2 state (wave 4) ----
    float w2i = 0, w2j = 0, w2f = 0, w2o = 0;
    float4 w2t = {0, 0, 0, 0}, b2v = {0, 0, 0, 0};
    float c2 = 0.f, h2 = 0.f;
    float zi_s = 0, zj_s = 0, zf_s = 0, zo_s = 0;

    if (w < 4) {
        const int col = w * kH + l;        // gate-major column
        w0 = W1[col];
        b1g = b1[col];
        #pragma unroll
        for (int k = 0; k < 32; ++k) wqv[k] = W1[(k + 1) * 256 + col];
        #pragma unroll
        for (int k = 0; k < 32; ++k) {
            float tmp = W1[(k + 33) * 256 + col];
            asm volatile("v_accvgpr_write_b32 %0, %1"
                         : "=a"(wqa[k]) : "v"(tmp));
        }
    } else {
        w2i = W2[l * 4 + 0];
        w2j = W2[l * 4 + 1];
        w2f = W2[l * 4 + 2];
        w2o = W2[l * 4 + 3];
        w2t = ((const float4*)W2)[kH];     // W2 row 64: h2 recurrent weights
        b2v = ((const float4*)b2)[0];
    }
    __syncthreads();

    for (int t = 0; t < kT; ++t) {
        const float xt = x_lds[t];
        // ---- redundant c1/h1 update (ALL 5 waves), lane l = unit l ----
        if (t > 0) {
            const int pb = (t - 1) & 1;
            const float ai = a_lds[pb][l];
            const float aj = a_lds[pb][kH + l];
            const float af = a_lds[pb][2 * kH + l];
            const float ao = a_lds[pb][3 * kH + l];
            c1 = fmaf(af, c1, ai * aj);
            h_new = ao * fast_tanh(c1);
        }
        if (w < 4) {
            // ---- layer-1 dot: h replicated in-wave, readlane broadcast ----
            float z0 = fmaf(xt, w0, b1g), z1 = 0.f, z2 = 0.f, z3 = 0.f;
            #pragma unroll
            for (int q = 0; q < 8; ++q) {
                z0 = fmaf(rlane(h_new, 4 * q + 0), wqv[4 * q + 0], z0);
                z1 = fmaf(rlane(h_new, 4 * q + 1), wqv[4 * q + 1], z1);
                z2 = fmaf(rlane(h_new, 4 * q + 2), wqv[4 * q + 2], z2);
                z3 = fmaf(rlane(h_new, 4 * q + 3), wqv[4 * q + 3], z3);
            }
            #pragma unroll
            for (int q = 0; q < 8; ++q) {
                float v0, v1, v2, v3;
                asm("v_accvgpr_read_b32 %0, %1" : "=v"(v0) : "a"(wqa[4 * q + 0]));
                asm("v_accvgpr_read_b32 %0, %1" : "=v"(v1) : "a"(wqa[4 * q + 1]));
                asm("v_accvgpr_read_b32 %0, %1" : "=v"(v2) : "a"(wqa[4 * q + 2]));
                asm("v_accvgpr_read_b32 %0, %1" : "=v"(v3) : "a"(wqa[4 * q + 3]));
                z0 = fmaf(rlane(h_new, 32 + 4 * q + 0), v0, z0);
                z1 = fmaf(rlane(h_new, 32 + 4 * q + 1), v1, z1);
                z2 = fmaf(rlane(h_new, 32 + 4 * q + 2), v2, z2);
                z3 = fmaf(rlane(h_new, 32 + 4 * q + 3), v3, z3);
            }
            const float z = (z0 + z1) + (z2 + z3);
            float a;
            if (w == 1)      a = fast_tanh(z);        // wave-uniform choice
            else if (w == 2) a = fast_sig(z + 1.0f);  // forget bias
            else             a = fast_sig(z);
            a_lds[t & 1][w * kH + l] = a;
        } else {
            // ---- stage B: recurrent c2/h2 for step t-2 (staged z) ----
            if (t >= 2) {
                const float zi = zi_s + h2 * w2t.x;
                const float zj = zj_s + h2 * w2t.y;
                const float zf = zf_s + h2 * w2t.z;
                const float zo = zo_s + h2 * w2t.w;
                c2 = fast_sig(zf + 1.0f) * c2 + fast_sig(zi) * fast_tanh(zj);
                h2 = fast_sig(zo) * fast_tanh(c2);
                if (l == 0) out_lds[t - 2] = h2;
            }
            // ---- stage A: layer-2 dot for step t-1 (uses h_new) ----
            if (t >= 1) {
                float p0 = h_new * w2i;
                float p1 = h_new * w2j;
                float p2 = h_new * w2f;
                float p3 = h_new * w2o;
                #pragma unroll
                for (int m = 1; m < 64; m <<= 1) {
                    p0 += __shfl_xor(p0, m);
                    p1 += __shfl_xor(p1, m);
                    p2 += __shfl_xor(p2, m);
                    p3 += __shfl_xor(p3, m);
                }
                zi_s = p0 + b2v.x;
                zj_s = p1 + b2v.y;
                zf_s = p2 + b2v.z;
                zo_s = p3 + b2v.w;
            }
        }
        __syncthreads();
    }

    // ---- epilogue (wave 4): finish steps T-2 and T-1 ----
    if (w == 4) {
        // final redundant h1 update from a(T-1)
        const int pb = (kT - 1) & 1;
        const float ai = a_lds[pb][l];
        const float aj = a_lds[pb][kH + l];
        const float af = a_lds[pb][2 * kH + l];
        const float ao = a_lds[pb][3 * kH + l];
        c1 = fmaf(af, c1, ai * aj);
        h_new = ao * fast_tanh(c1);
        {   // stage B for T-2 (z staged in the last loop iteration)
            const float zi = zi_s + h2 * w2t.x;
            const float zj = zj_s + h2 * w2t.y;
            const float zf = zf_s + h2 * w2t.z;
            const float zo = zo_s + h2 * w2t.w;
            c2 = fast_sig(zf + 1.0f) * c2 + fast_sig(zi) * fast_tanh(zj);
            h2 = fast_sig(zo) * fast_tanh(c2);
            if (l == 0) out_lds[kT - 2] = h2;
        }
        {   // stage A + B for T-1
            float p0 = h_new * w2i;
            float p1 = h_new * w2j;
            float p2 = h_new * w2f;
            float p3 = h_new * w2o;
            #pragma unroll
            for (int m = 1; m < 64; m <<= 1) {
                p0 += __shfl_xor(p0, m);
                p1 += __shfl_xor(p1, m);
                p2 += __shfl_xor(p2, m);
                p3 += __shfl_xor(p3, m);
            }
            const float zi = p0 + b2v.x + h2 * w2t.x;
            const float zj = p1 + b2v.y + h2 * w2t.y;
            const float zf = p2 + b2v.z + h2 * w2t.z;
            const float zo = p3 + b2v.w + h2 * w2t.w;
            c2 = fast_sig(zf + 1.0f) * c2 + fast_sig(zi) * fast_tanh(zj);
            h2 = fast_sig(zo) * fast_tanh(c2);
            if (l == 0) out_lds[kT - 1] = h2;
        }
    }
    __syncthreads();
    // ---- single coalesced output flush ----
    for (int i = tid; i < kT; i += kThreads) outg[i] = out_lds[i];
}

extern "C" void kernel_launch(void* const* d_in, const int* in_sizes, int n_in,
                              void* d_out, int out_size, void* d_ws, size_t ws_size,
                              hipStream_t stream) {
    const float* x  = (const float*)d_in[0];
    const float* W1 = (const float*)d_in[1];
    const float* b1 = (const float*)d_in[2];
    const float* W2 = (const float*)d_in[3];
    const float* b2 = (const float*)d_in[4];
    float* out = (float*)d_out;
    lstm2_kernel<<<kB, kThreads, 0, stream>>>(x, W1, b1, W2, b2, out);
}

// Round 9
// 1452.908 us; speedup vs baseline: 1.1363x; 1.1363x over previous
//
#include <hip/hip_runtime.h>

// 2-layer stacked LSTM: B=256, T=2048, H=64, layer2 hidden=1.
// One block per batch element (256 blocks), 512 threads (8 waves).
//
// Constraints learned in rounds 1-8 (all satisfied simultaneously here):
//  (1) LDS billing is per-op bandwidth (~85-110 B/cyc/CU): h must NOT be
//      delivered per-lane from LDS (r1-r5 floor ~900 cyc/step).
//  (2) Weights resident only when lane demand <= 64 VGPRs: 32 wt/lane max
//      (r5:48, r7:44 resident; 64-wt designs always got squeezed).
//  (3) One LDS round trip + one barrier per step (each extra ~ +250 cyc).
//
// Wave v: gate g=v>>1, row-half hv=v&1 (WAVE-uniform -> readlane with
// immediate lane indices, templated on hv). Lane l = unit l.
// Per step: PRE: 32x(v_readlane+v_fmac) partial dot (rows 32hv..32hv+31 of
// col g*64+l) -> 1 b32 write into zbuf. BARRIER. POST: every wave reads the
// 4 gate totals (4x ds_read_b64, 2-way free), activates and updates c1/h1
// REDUNDANTLY -> h1 replicated in-register in all waves, no h LDS, no
// gate-exchange, one barrier.
// Layer 2: stage A (4 dots of 64) on wave 7 via DPP wave-reduction (VALU
// pipe, no ds_bpermute butterfly), staged to a 16B LDS slot; stage B
// (recurrent c2/h2, 2 steps behind) on wave 1 (different SIMD). Outputs
// staged in out_lds, single coalesced flush.
constexpr int kT = 2048;
constexpr int kB = 256;
constexpr int kH = 64;
constexpr int kThreads = 512;

__device__ __forceinline__ float fast_sig(float x) {
    return __builtin_amdgcn_rcpf(1.0f + __expf(-x));
}
__device__ __forceinline__ float fast_tanh(float x) {
    float t = __expf(2.0f * x);
    return 1.0f - 2.0f * __builtin_amdgcn_rcpf(t + 1.0f);
}
__device__ __forceinline__ float rlane(float v, int k) {
    return __int_as_float(__builtin_amdgcn_readlane(__float_as_int(v), k));
}

// wave64 sum via DPP (VALU pipe, no DS ops); result broadcast to all lanes.
#define DPP_ADD(x, ctrl, rmask)                                              \
    x += __int_as_float(__builtin_amdgcn_update_dpp(                         \
        0, __float_as_int(x), ctrl, rmask, 0xf, false))
__device__ __forceinline__ float wave_sum_dpp(float x) {
    DPP_ADD(x, 0x111, 0xf);   // row_shr:1
    DPP_ADD(x, 0x112, 0xf);   // row_shr:2
    DPP_ADD(x, 0x114, 0xf);   // row_shr:4
    DPP_ADD(x, 0x118, 0xf);   // row_shr:8  -> lane15 of each row16 = row sum
    DPP_ADD(x, 0x142, 0xa);   // row_bcast:15 into rows 1,3
    DPP_ADD(x, 0x143, 0xc);   // row_bcast:31 into rows 2,3 -> lane63 = total
    return rlane(x, 63);
}

// partial dot with compile-time readlane base (RB = 0 or 32)
template <int RB>
__device__ __forceinline__ float qdot(float h, const float* wq) {
    float z0 = 0.f, z1 = 0.f, z2 = 0.f, z3 = 0.f;
    #pragma unroll
    for (int q = 0; q < 8; ++q) {
        z0 = fmaf(rlane(h, RB + 4 * q + 0), wq[4 * q + 0], z0);
        z1 = fmaf(rlane(h, RB + 4 * q + 1), wq[4 * q + 1], z1);
        z2 = fmaf(rlane(h, RB + 4 * q + 2), wq[4 * q + 2], z2);
        z3 = fmaf(rlane(h, RB + 4 * q + 3), wq[4 * q + 3], z3);
    }
    return (z0 + z1) + (z2 + z3);
}

__global__ __launch_bounds__(kThreads) void lstm2_kernel(
    const float* __restrict__ x, const float* __restrict__ W1,
    const float* __restrict__ b1, const float* __restrict__ W2,
    const float* __restrict__ b2, float* __restrict__ out)
{
    __shared__ float  x_lds[kT];        // input row
    __shared__ float  out_lds[kT];      // staged outputs
    __shared__ float2 zbuf[2][256];     // {hv0,hv1} partial per column
    __shared__ float4 z2stage[2];       // staged layer-2 dot (wave7 -> wave1)
    __shared__ float4 w2misc[2];        // {w2t, b2} for wave 1 (saves VGPRs)

    const int tid = threadIdx.x;
    const int b = blockIdx.x;
    const float* xg = x + (size_t)b * kT;
    float* outg = out + (size_t)b * kT;

    for (int i = tid; i < kT; i += kThreads) x_lds[i] = xg[i];
    if (tid == 0) {
        w2misc[0] = ((const float4*)W2)[kH];   // h2 recurrent row
        w2misc[1] = ((const float4*)b2)[0];
    }

    const int v  = tid >> 6;      // wave 0..7
    const int l  = tid & 63;      // lane = unit
    const int g  = v >> 1;        // gate
    const int hv = v & 1;         // row half (wave-uniform)
    const int col = g * kH + l;   // gate-major column

    // ---- 32 register-resident weights: rows 32hv+1 .. 32hv+32 of col ----
    float wq[32];
    #pragma unroll
    for (int q = 0; q < 32; ++q) wq[q] = W1[(hv * 32 + q + 1) * 256 + col];
    float w0 = 0.f, b1g = 0.f;
    if (hv == 0) { w0 = W1[col]; b1g = b1[col]; }

    float c1 = 0.f, h_new = 0.f;  // replicated in every wave, lane = unit

    // wave-7 extras: layer-2 input weights (per-lane row of W2)
    float w2a = 0.f, w2b = 0.f, w2c = 0.f, w2d = 0.f;
    if (v == 7) {
        w2a = W2[l * 4 + 0]; w2b = W2[l * 4 + 1];
        w2c = W2[l * 4 + 2]; w2d = W2[l * 4 + 3];
    }
    float c2 = 0.f, h2 = 0.f;     // wave-1 layer-2 recurrent state
    __syncthreads();

    for (int t = 0; t < kT; ++t) {
        const int cb = t & 1;
        // ================= PRE: partial dots =================
        {
            float zp = (hv == 0) ? qdot<0>(h_new, wq) : qdot<32>(h_new, wq);
            if (hv == 0) zp += fmaf(x_lds[t], w0, b1g);  // x-term + bias
            ((float*)&zbuf[cb][col])[hv] = zp;           // 1 b32 write
        }
        if (v == 7 && t >= 1) {
            // layer-2 stage A for step t-1 (h_new = h1(t-1)); DPP reduce
            const float s0 = wave_sum_dpp(h_new * w2a);
            const float s1 = wave_sum_dpp(h_new * w2b);
            const float s2 = wave_sum_dpp(h_new * w2c);
            const float s3 = wave_sum_dpp(h_new * w2d);
            if (l == 0) z2stage[(t - 1) & 1] = make_float4(s0, s1, s2, s3);
        }
        if (v == 1 && t >= 2) {
            // layer-2 stage B for step t-2 (staged A crossed barrier t-1)
            const float4 zs = z2stage[(t - 2) & 1];
            const float4 w2t = w2misc[0];
            const float4 b2v = w2misc[1];
            const float zi = zs.x + b2v.x + h2 * w2t.x;
            const float zj = zs.y + b2v.y + h2 * w2t.y;
            const float zf = zs.z + b2v.z + h2 * w2t.z;
            const float zo = zs.w + b2v.w + h2 * w2t.w;
            c2 = fast_sig(zf + 1.0f) * c2 + fast_sig(zi) * fast_tanh(zj);
            h2 = fast_sig(zo) * fast_tanh(c2);
            if (l == 0) out_lds[t - 2] = h2;
        }
        __syncthreads();
        // ================= POST: redundant activate + update =================
        {
            const float2 pi = zbuf[cb][l];
            const float2 pj = zbuf[cb][kH + l];
            const float2 pf = zbuf[cb][2 * kH + l];
            const float2 po = zbuf[cb][3 * kH + l];
            const float ai = fast_sig(pi.x + pi.y);
            const float aj = fast_tanh(pj.x + pj.y);
            const float af = fast_sig(pf.x + pf.y + 1.0f);  // forget bias
            const float ao = fast_sig(po.x + po.y);
            c1 = fmaf(af, c1, ai * aj);
            h_new = ao * fast_tanh(c1);
        }
    }

    // ---- epilogue ----
    if (v == 7) {   // stage A for T-1 (h_new = h1(T-1))
        const float s0 = wave_sum_dpp(h_new * w2a);
        const float s1 = wave_sum_dpp(h_new * w2b);
        const float s2 = wave_sum_dpp(h_new * w2c);
        const float s3 = wave_sum_dpp(h_new * w2d);
        if (l == 0) z2stage[(kT - 1) & 1] = make_float4(s0, s1, s2, s3);
    }
    __syncthreads();
    if (v == 1) {   // stage B for T-2 and T-1
        const float4 w2t = w2misc[0];
        const float4 b2v = w2misc[1];
        #pragma unroll
        for (int e = 0; e < 2; ++e) {
            const int tt = kT - 2 + e;
            const float4 zs = z2stage[tt & 1];
            const float zi = zs.x + b2v.x + h2 * w2t.x;
            const float zj = zs.y + b2v.y + h2 * w2t.y;
            const float zf = zs.z + b2v.z + h2 * w2t.z;
            const float zo = zs.w + b2v.w + h2 * w2t.w;
            c2 = fast_sig(zf + 1.0f) * c2 + fast_sig(zi) * fast_tanh(zj);
            h2 = fast_sig(zo) * fast_tanh(c2);
            if (l == 0) out_lds[tt] = h2;
        }
    }
    __syncthreads();
    // ---- single coalesced output flush ----
    for (int i = tid; i < kT; i += kThreads) outg[i] = out_lds[i];
}

extern "C" void kernel_launch(void* const* d_in, const int* in_sizes, int n_in,
                              void* d_out, int out_size, void* d_ws, size_t ws_size,
                              hipStream_t stream) {
    const float* x  = (const float*)d_in[0];
    const float* W1 = (const float*)d_in[1];
    const float* b1 = (const float*)d_in[2];
    const float* W2 = (const float*)d_in[3];
    const float* b2 = (const float*)d_in[4];
    float* out = (float*)d_out;
    lstm2_kernel<<<kB, kThreads, 0, stream>>>(x, W1, b1, W2, b2, out);
}